// Round 4
// baseline (224.177 us; speedup 1.0000x reference)
//
#include <hip/hip_runtime.h>

// Problem constants (from reference)
#define V_ 12
#define N_ 80000
#define C_ 256
#define H_ 128
#define W_ 128
#define G_ 4096
#define M_ 512
#define E_ 200000
#define L_ 20
#define HD 128            // C/2 hidden dim
#define NBUCK (V_ * 1024) // line-buckets: (v, y, x>>4) ; 1024 = 128*8 per view
#define BCAP 32           // max group-items per line-bucket (Poisson λ=4; P(>=32)~1e-16)
#define PCAP 32           // max pairs per point (Poisson λ=2.5; P(>=32)~1e-19)
#define GV (G_ * V_)

// ---------------------------------------------------------------------------
// Kernel 1: build both inverted indexes in one pass.
//  t < GV          : (g,v) item -> line-bucket b=(v,y,x>>4); store {g, x&15, scale}
//  GV <= t < GV+E  : pair e -> per-point list; store mask id
// Also accumulates mcnt[m] (groups per mask) from the v==0 thread of each g.
__global__ void build_kernel(const float* __restrict__ is_seen,
                             const int* __restrict__ coords,
                             const int* __restrict__ centers,
                             const int* __restrict__ g2m,
                             const int* __restrict__ pair_mask,
                             const int* __restrict__ pair_point,
                             int* __restrict__ bcount,
                             int* __restrict__ bmeta,
                             float* __restrict__ bscale,
                             int* __restrict__ pcount,
                             int* __restrict__ pitems,
                             float* __restrict__ mcnt) {
  int t = blockIdx.x * blockDim.x + threadIdx.x;
  if (t < GV) {
    int g = t & (G_ - 1);   // g fast -> coalesced-ish centers reads
    int v = t >> 12;
    int n = centers[g];
    float wsum = 0.f;
#pragma unroll
    for (int vv = 0; vv < V_; ++vv) wsum += is_seen[(size_t)vv * N_ + n];
    float s = is_seen[(size_t)v * N_ + n] / (wsum + 1e-6f);
    if (v == 0) atomicAdd(&mcnt[g2m[g]], 1.0f);
    int x = coords[((size_t)v * N_ + n) * 2 + 0];
    int y = coords[((size_t)v * N_ + n) * 2 + 1];
    int b = (v << 10) | (y << 3) | (x >> 4);
    int slot = atomicAdd(&bcount[b], 1);
    if (slot < BCAP) {
      bmeta[b * BCAP + slot] = g | ((x & 15) << 12);  // g:12 bits, xi:4 bits
      bscale[b * BCAP + slot] = s;
    }
  } else if (t < GV + E_) {
    int e = t - GV;
    int p = pair_point[e];
    int slot = atomicAdd(&pcount[p], 1);
    if (slot < PCAP) pitems[(size_t)p * PCAP + slot] = pair_mask[e];
  }
}

// ---------------------------------------------------------------------------
// Kernel 2: line-bucket gather, ATOMIC-FREE. One block per (v,y,x>>4) bucket;
// thread c owns channel c. Each needed 64B img line is read EXACTLY ONCE,
// parked in LDS (stride 17 -> conflict-free), then each (g,v) item's scaled
// feature is written ONCE (plain coalesced store) to pvg[g][v][c]. Every
// (g,v) pair lands in exactly one bucket slot, so pvg needs no init.
__global__ void gather_kernel(const float* __restrict__ img,
                              const int* __restrict__ bcount,
                              const int* __restrict__ bmeta,
                              const float* __restrict__ bscale,
                              float* __restrict__ pvg) {
  int b = blockIdx.x;
  int cnt = bcount[b];
  if (cnt == 0) return;
  if (cnt > BCAP) cnt = BCAP;
  int c = threadIdx.x;              // 0..255
  int v = b >> 10;
  int y = (b >> 3) & 127;
  int x0 = (b & 7) << 4;
  __shared__ float lines[C_ * 17];  // per-thread 16 floats, stride 17
  const float4* src = (const float4*)(img + (((size_t)(v * C_ + c)) * H_ + y) * W_ + x0);
  float4 q0 = src[0], q1 = src[1], q2 = src[2], q3 = src[3];
  float* lr = &lines[c * 17];
  lr[0] = q0.x; lr[1] = q0.y; lr[2] = q0.z; lr[3] = q0.w;
  lr[4] = q1.x; lr[5] = q1.y; lr[6] = q1.z; lr[7] = q1.w;
  lr[8] = q2.x; lr[9] = q2.y; lr[10] = q2.z; lr[11] = q2.w;
  lr[12] = q3.x; lr[13] = q3.y; lr[14] = q3.z; lr[15] = q3.w;
  // Only the owning thread reads its own lr[] -> no __syncthreads needed.
  for (int it = 0; it < cnt; ++it) {
    int meta = bmeta[b * BCAP + it];
    float s = bscale[b * BCAP + it];
    int g = meta & 4095;
    int xi = (meta >> 12) & 15;
    pvg[((size_t)g * V_ + v) * C_ + c] = lr[xi] * s;
  }
}

// ---------------------------------------------------------------------------
// Kernel 2b: reduce views per group, then group -> mask (only 1M atomics,
// 12.6x fewer than the old per-(g,v,c) scheme).
__global__ void greduce_kernel(const float* __restrict__ pvg,
                               const int* __restrict__ g2m,
                               float* __restrict__ msum) {
  int g = blockIdx.x;        // 0..G-1
  int c = threadIdx.x;       // 0..C-1
  const float* base = pvg + (size_t)g * V_ * C_ + c;
  float s = 0.f;
#pragma unroll
  for (int v = 0; v < V_; ++v) s += base[(size_t)v * C_];
  atomicAdd(&msum[(size_t)g2m[g] * C_ + c], s);
}

// ---------------------------------------------------------------------------
// Kernel 3: mW1[m] = (where(mcnt>0, msum/max(mcnt,1), 0)) @ W1   (512 x 128)
__global__ void maskw1_kernel(const float* __restrict__ msum,
                              const float* __restrict__ mcnt,
                              const float* __restrict__ W1,
                              float* __restrict__ mW1) {
  int m = blockIdx.x;        // 0..M-1
  int j = threadIdx.x;       // 0..HD-1
  __shared__ float row[C_];
  row[j] = msum[(size_t)m * C_ + j];
  row[j + HD] = msum[(size_t)m * C_ + j + HD];
  __syncthreads();
  float cv = mcnt[m];
  float inv = cv > 0.f ? 1.0f / fmaxf(cv, 1.0f) : 0.f;
  float acc = 0.f;
  for (int c = 0; c < C_; ++c) {
    acc += row[c] * W1[(size_t)c * HD + j];
  }
  mW1[(size_t)m * HD + j] = acc * inv;
}

// ---------------------------------------------------------------------------
// Kernel 4: one wave per point. Gather & sum the point's mW1 rows (avg 2.5,
// L2-resident 256KB table), relu(mean + b1) into LDS, then 20 lanes do the
// 128x20 layer-2 matvec and write the 20 outputs. No atomics, no fsum buffer.
__global__ void point_mlp_kernel(const int* __restrict__ pcount,
                                 const int* __restrict__ pitems,
                                 const float* __restrict__ mW1,
                                 const float* __restrict__ b1,
                                 const float* __restrict__ W2,
                                 const float* __restrict__ b2,
                                 float* __restrict__ out) {
  int wave = threadIdx.x >> 6;
  int lane = threadIdx.x & 63;
  int p = blockIdx.x * 4 + wave;   // N = 80000 = 20000*4 exactly
  __shared__ float hbuf[4][130];
  int cnt = pcount[p];
  int k = cnt < PCAP ? cnt : PCAP;
  float hx = 0.f, hy = 0.f;
  const int* lst = &pitems[(size_t)p * PCAP];
  for (int it = 0; it < k; ++it) {
    int m = lst[it];
    float2 r = ((const float2*)(mW1 + (size_t)m * HD))[lane];
    hx += r.x;
    hy += r.y;
  }
  float invc = 1.0f / fmaxf((float)cnt, 1e-6f);
  hbuf[wave][2 * lane]     = fmaxf(hx * invc + b1[2 * lane], 0.f);
  hbuf[wave][2 * lane + 1] = fmaxf(hy * invc + b1[2 * lane + 1], 0.f);
  __syncthreads();
  if (lane < L_) {
    float o = b2[lane];
    const float* hb = hbuf[wave];
#pragma unroll 8
    for (int kk = 0; kk < HD; ++kk) o += hb[kk] * W2[kk * L_ + lane];
    out[(size_t)p * L_ + lane] = o;
  }
}

// ---------------------------------------------------------------------------
extern "C" void kernel_launch(void* const* d_in, const int* in_sizes, int n_in,
                              void* d_out, int out_size, void* d_ws, size_t ws_size,
                              hipStream_t stream) {
  const float* img      = (const float*)d_in[0];
  const float* is_seen  = (const float*)d_in[1];
  const float* W1       = (const float*)d_in[2];
  const float* b1       = (const float*)d_in[3];
  const float* W2       = (const float*)d_in[4];
  const float* b2       = (const float*)d_in[5];
  const int* coords     = (const int*)d_in[6];
  const int* centers    = (const int*)d_in[7];
  const int* g2m        = (const int*)d_in[8];
  const int* pair_mask  = (const int*)d_in[9];
  const int* pair_point = (const int*)d_in[10];
  float* out = (float*)d_out;

  // Workspace layout:
  // floats: msum[M*C] | mcnt[M] | mW1[M*HD] | bscale[NBUCK*BCAP] | pvg[G*V*C]
  // ints  : bcount[NBUCK] | pcount[N] | bmeta[NBUCK*BCAP] | pitems[N*PCAP]
  float* ws     = (float*)d_ws;
  float* msum   = ws;
  float* mcnt   = msum + (size_t)M_ * C_;
  float* mW1    = mcnt + M_;
  float* bscale = mW1 + (size_t)M_ * HD;
  float* pvg    = bscale + (size_t)NBUCK * BCAP;
  int*   bcount = (int*)(pvg + (size_t)G_ * V_ * C_);
  int*   pcount = bcount + NBUCK;
  int*   bmeta  = pcount + N_;
  int*   pitems = bmeta + (size_t)NBUCK * BCAP;

  // Zero accumulators + counters (2 contiguous memsets; run every call).
  // pvg needs NO init: every (g,v,c) element is written exactly once.
  hipMemsetAsync(msum, 0, ((size_t)M_ * C_ + M_) * sizeof(float), stream);
  hipMemsetAsync(bcount, 0, ((size_t)NBUCK + N_) * sizeof(int), stream);

  build_kernel<<<(GV + E_ + 255) / 256, 256, 0, stream>>>(
      is_seen, coords, centers, g2m, pair_mask, pair_point,
      bcount, bmeta, bscale, pcount, pitems, mcnt);
  gather_kernel<<<NBUCK, C_, 0, stream>>>(img, bcount, bmeta, bscale, pvg);
  greduce_kernel<<<G_, C_, 0, stream>>>(pvg, g2m, msum);
  maskw1_kernel<<<M_, HD, 0, stream>>>(msum, mcnt, W1, mW1);
  point_mlp_kernel<<<N_ / 4, 256, 0, stream>>>(pcount, pitems, mW1, b1, W2, b2, out);
}

// Round 5
// 204.686 us; speedup vs baseline: 1.0952x; 1.0952x over previous
//
#include <hip/hip_runtime.h>

// Problem constants (from reference)
#define V_ 12
#define N_ 80000
#define C_ 256
#define H_ 128
#define W_ 128
#define G_ 4096
#define M_ 512
#define E_ 200000
#define L_ 20
#define HD 128            // C/2 hidden dim
#define NROW (V_ * H_)    // row-buckets: (v, y) ; 1536
#define RCAP 128          // max items per row-bucket (Poisson λ=32; P(>128) ~ e^-81)
#define PCAP 32           // max pairs per point (Poisson λ=2.5; P(>=32) ~ 1e-19)
#define GV (G_ * V_)

// ---------------------------------------------------------------------------
// Kernel 1: build both inverted indexes in one pass.
//  t < GV          : (g,v) item -> row-bucket b=(v,y); store {m, x, scale}
//  GV <= t < GV+E  : pair e -> per-point list; store mask id
// Also accumulates mcnt[m] (groups per mask) from the v==0 thread of each g.
__global__ void build_kernel(const float* __restrict__ is_seen,
                             const int* __restrict__ coords,
                             const int* __restrict__ centers,
                             const int* __restrict__ g2m,
                             const int* __restrict__ pair_mask,
                             const int* __restrict__ pair_point,
                             int* __restrict__ rcount,
                             int* __restrict__ rmeta,
                             float* __restrict__ rscale,
                             int* __restrict__ pcount,
                             int* __restrict__ pitems,
                             float* __restrict__ mcnt) {
  int t = blockIdx.x * blockDim.x + threadIdx.x;
  if (t < GV) {
    int g = t & (G_ - 1);   // g fast -> coalesced-ish centers reads
    int v = t >> 12;
    int n = centers[g];
    float wsum = 0.f;
#pragma unroll
    for (int vv = 0; vv < V_; ++vv) wsum += is_seen[(size_t)vv * N_ + n];
    float s = is_seen[(size_t)v * N_ + n] / (wsum + 1e-6f);
    int m = g2m[g];
    if (v == 0) atomicAdd(&mcnt[m], 1.0f);
    int x = coords[((size_t)v * N_ + n) * 2 + 0];
    int y = coords[((size_t)v * N_ + n) * 2 + 1];
    int b = (v << 7) | y;
    int slot = atomicAdd(&rcount[b], 1);
    if (slot < RCAP) {
      rmeta[b * RCAP + slot] = m | (x << 9);  // m:9 bits, x:7 bits
      rscale[b * RCAP + slot] = s;
    }
  } else if (t < GV + E_) {
    int e = t - GV;
    int p = pair_point[e];
    int slot = atomicAdd(&pcount[p], 1);
    if (slot < PCAP) pitems[(size_t)p * PCAP + slot] = pair_mask[e];
  }
}

// ---------------------------------------------------------------------------
// Kernel 2: row-bucket gather. One block per (v,y) x 128-channel-half.
// Each thread streams a CONTIGUOUS 256 B half-row (16 x float4) into a padded
// LDS tile (stride 129 -> conflict-free), so DRAM sees 256B-sequential
// per-thread streams instead of scattered 64B lines. Then waves distribute:
// 2 items x 128 channels per pass, 256B-contiguous atomics into msum.
__global__ void gather_kernel(const float* __restrict__ img,
                              const int* __restrict__ rcount,
                              const int* __restrict__ rmeta,
                              const float* __restrict__ rscale,
                              float* __restrict__ msum) {
  int bid = blockIdx.x;
  int b = bid >> 1;            // row-bucket (v,y)
  int cg = bid & 1;            // channel half: 0 -> ch 0..127, 1 -> ch 128..255
  int cnt = rcount[b];
  if (cnt == 0) return;        // uniform branch
  if (cnt > RCAP) cnt = RCAP;
  int v = b >> 7;
  int y = b & 127;
  int t = threadIdx.x;
  int cl = t & 127;            // channel within half
  int q = t >> 7;              // 0/1: which 64-float half of the W row
  __shared__ float rows[128 * 129];  // 128 channels x 128 floats, pad stride 129
  const float4* src = (const float4*)(img +
      (((size_t)(v * C_ + cg * 128 + cl)) * H_ + y) * W_ + q * 64);
  float* dst = &rows[cl * 129 + q * 64];
#pragma unroll
  for (int i = 0; i < 16; ++i) {
    float4 u = src[i];
    dst[i * 4 + 0] = u.x; dst[i * 4 + 1] = u.y;
    dst[i * 4 + 2] = u.z; dst[i * 4 + 3] = u.w;
  }
  __syncthreads();
  // Distribution: waves 0,1 (t<128) handle items it, waves 2,3 items it+1.
  int item_off = t >> 7;
  for (int it = item_off; it < cnt; it += 2) {
    int meta = rmeta[b * RCAP + it];
    float s = rscale[b * RCAP + it];
    int m = meta & 511;
    int x = (meta >> 9) & 127;
    float val = rows[cl * 129 + x] * s;
    atomicAdd(&msum[(size_t)m * C_ + cg * 128 + cl], val);
  }
}

// ---------------------------------------------------------------------------
// Kernel 3: mW1[m] = (where(mcnt>0, msum/max(mcnt,1), 0)) @ W1   (512 x 128)
__global__ void maskw1_kernel(const float* __restrict__ msum,
                              const float* __restrict__ mcnt,
                              const float* __restrict__ W1,
                              float* __restrict__ mW1) {
  int m = blockIdx.x;        // 0..M-1
  int j = threadIdx.x;       // 0..HD-1
  __shared__ float row[C_];
  row[j] = msum[(size_t)m * C_ + j];
  row[j + HD] = msum[(size_t)m * C_ + j + HD];
  __syncthreads();
  float cv = mcnt[m];
  float inv = cv > 0.f ? 1.0f / fmaxf(cv, 1.0f) : 0.f;
  float acc = 0.f;
  for (int c = 0; c < C_; ++c) {
    acc += row[c] * W1[(size_t)c * HD + j];
  }
  mW1[(size_t)m * HD + j] = acc * inv;
}

// ---------------------------------------------------------------------------
// Kernel 4: one wave per point. Gather & sum the point's mW1 rows (avg 2.5,
// L2-resident 256KB table), relu(mean + b1) into LDS, then 20 lanes do the
// 128x20 layer-2 matvec and write the 20 outputs. No atomics, no fsum buffer.
__global__ void point_mlp_kernel(const int* __restrict__ pcount,
                                 const int* __restrict__ pitems,
                                 const float* __restrict__ mW1,
                                 const float* __restrict__ b1,
                                 const float* __restrict__ W2,
                                 const float* __restrict__ b2,
                                 float* __restrict__ out) {
  int wave = threadIdx.x >> 6;
  int lane = threadIdx.x & 63;
  int p = blockIdx.x * 4 + wave;   // N = 80000 = 20000*4 exactly
  __shared__ float hbuf[4][130];
  int cnt = pcount[p];
  int k = cnt < PCAP ? cnt : PCAP;
  float hx = 0.f, hy = 0.f;
  const int* lst = &pitems[(size_t)p * PCAP];
  for (int it = 0; it < k; ++it) {
    int m = lst[it];
    float2 r = ((const float2*)(mW1 + (size_t)m * HD))[lane];
    hx += r.x;
    hy += r.y;
  }
  float invc = 1.0f / fmaxf((float)cnt, 1e-6f);
  hbuf[wave][2 * lane]     = fmaxf(hx * invc + b1[2 * lane], 0.f);
  hbuf[wave][2 * lane + 1] = fmaxf(hy * invc + b1[2 * lane + 1], 0.f);
  __syncthreads();
  if (lane < L_) {
    float o = b2[lane];
    const float* hb = hbuf[wave];
#pragma unroll 8
    for (int kk = 0; kk < HD; ++kk) o += hb[kk] * W2[kk * L_ + lane];
    out[(size_t)p * L_ + lane] = o;
  }
}

// ---------------------------------------------------------------------------
extern "C" void kernel_launch(void* const* d_in, const int* in_sizes, int n_in,
                              void* d_out, int out_size, void* d_ws, size_t ws_size,
                              hipStream_t stream) {
  const float* img      = (const float*)d_in[0];
  const float* is_seen  = (const float*)d_in[1];
  const float* W1       = (const float*)d_in[2];
  const float* b1       = (const float*)d_in[3];
  const float* W2       = (const float*)d_in[4];
  const float* b2       = (const float*)d_in[5];
  const int* coords     = (const int*)d_in[6];
  const int* centers    = (const int*)d_in[7];
  const int* g2m        = (const int*)d_in[8];
  const int* pair_mask  = (const int*)d_in[9];
  const int* pair_point = (const int*)d_in[10];
  float* out = (float*)d_out;

  // Workspace layout:
  // floats: msum[M*C] | mcnt[M] | mW1[M*HD] | rscale[NROW*RCAP]
  // ints  : rcount[NROW] | pcount[N] | rmeta[NROW*RCAP] | pitems[N*PCAP]
  float* ws     = (float*)d_ws;
  float* msum   = ws;
  float* mcnt   = msum + (size_t)M_ * C_;
  float* mW1    = mcnt + M_;
  float* rscale = mW1 + (size_t)M_ * HD;
  int*   rcount = (int*)(rscale + (size_t)NROW * RCAP);
  int*   pcount = rcount + NROW;
  int*   rmeta  = pcount + N_;
  int*   pitems = rmeta + (size_t)NROW * RCAP;

  // Zero accumulators + counters (2 contiguous memsets; run every call)
  hipMemsetAsync(msum, 0, ((size_t)M_ * C_ + M_) * sizeof(float), stream);
  hipMemsetAsync(rcount, 0, ((size_t)NROW + N_) * sizeof(int), stream);

  build_kernel<<<(GV + E_ + 255) / 256, 256, 0, stream>>>(
      is_seen, coords, centers, g2m, pair_mask, pair_point,
      rcount, rmeta, rscale, pcount, pitems, mcnt);
  gather_kernel<<<NROW * 2, 256, 0, stream>>>(img, rcount, rmeta, rscale, msum);
  maskw1_kernel<<<M_, HD, 0, stream>>>(msum, mcnt, W1, mW1);
  point_mlp_kernel<<<N_ / 4, 256, 0, stream>>>(pcount, pitems, mW1, b1, W2, b2, out);
}

// Round 6
// 179.338 us; speedup vs baseline: 1.2500x; 1.1413x over previous
//
#include <hip/hip_runtime.h>

// Problem constants (from reference)
#define V_ 12
#define N_ 80000
#define C_ 256
#define H_ 128
#define W_ 128
#define G_ 4096
#define M_ 512
#define E_ 200000
#define L_ 20
#define HD 128            // C/2 hidden dim
#define NROW (V_ * H_)    // row-buckets: (v, y) ; 1536
#define RCAP 128          // max items per row-bucket (Poisson λ=32; P(>128) ~ e^-81)
#define PCAP 32           // max pairs per point (Poisson λ=2.5; P(>=32) ~ 1e-19)
#define GV (G_ * V_)
#define QCH 64            // channels per gather block (quarter of C)

// ---------------------------------------------------------------------------
// Kernel 1: build both inverted indexes in one pass.
//  t < GV          : (g,v) item -> row-bucket b=(v,y); store {m, x, scale}
//  GV <= t < GV+E  : pair e -> per-point list; store mask id
// Also accumulates mcnt[m] (groups per mask) from the v==0 thread of each g.
__global__ void build_kernel(const float* __restrict__ is_seen,
                             const int* __restrict__ coords,
                             const int* __restrict__ centers,
                             const int* __restrict__ g2m,
                             const int* __restrict__ pair_mask,
                             const int* __restrict__ pair_point,
                             int* __restrict__ rcount,
                             int* __restrict__ rmeta,
                             float* __restrict__ rscale,
                             int* __restrict__ pcount,
                             int* __restrict__ pitems,
                             float* __restrict__ mcnt) {
  int t = blockIdx.x * blockDim.x + threadIdx.x;
  if (t < GV) {
    int g = t & (G_ - 1);   // g fast -> coalesced-ish centers reads
    int v = t >> 12;
    int n = centers[g];
    float wsum = 0.f;
#pragma unroll
    for (int vv = 0; vv < V_; ++vv) wsum += is_seen[(size_t)vv * N_ + n];
    float s = is_seen[(size_t)v * N_ + n] / (wsum + 1e-6f);
    int m = g2m[g];
    if (v == 0) atomicAdd(&mcnt[m], 1.0f);
    int x = coords[((size_t)v * N_ + n) * 2 + 0];
    int y = coords[((size_t)v * N_ + n) * 2 + 1];
    int b = (v << 7) | y;
    int slot = atomicAdd(&rcount[b], 1);
    if (slot < RCAP) {
      rmeta[b * RCAP + slot] = m | (x << 9);  // m:9 bits, x:7 bits
      rscale[b * RCAP + slot] = s;
    }
  } else if (t < GV + E_) {
    int e = t - GV;
    int p = pair_point[e];
    int slot = atomicAdd(&pcount[p], 1);
    if (slot < PCAP) pitems[(size_t)p * PCAP + slot] = pair_mask[e];
  }
}

// ---------------------------------------------------------------------------
// Kernel 2: row-bucket gather, INSTRUCTION-COALESCED. One block per (v,y) x
// 64-channel quarter. The 64ch x 128float slab is loaded by flat float4 index
// with CONSECUTIVE LANES ON CONSECUTIVE ADDRESSES: each 64-lane instruction
// covers 1 KB contiguous = 16 cache lines (4 lanes/line merged at TCP),
// instead of 64 scattered lines. This cuts distinct-line lookups 4x (the
// measured ~105 G-lookup/s ceiling was the r3/r5 limiter). LDS tile stride
// 129: distribution reads conflict-free; write phase 4-way (hidden).
__global__ void gather_kernel(const float* __restrict__ img,
                              const int* __restrict__ rcount,
                              const int* __restrict__ rmeta,
                              const float* __restrict__ rscale,
                              float* __restrict__ msum) {
  int bid = blockIdx.x;
  int b = bid >> 2;            // row-bucket (v,y)
  int cg = bid & 3;            // channel quarter: ch in [cg*64, cg*64+64)
  int cnt = rcount[b];
  if (cnt == 0) return;        // uniform branch
  if (cnt > RCAP) cnt = RCAP;
  int v = b >> 7;
  int y = b & 127;
  int t = threadIdx.x;
  __shared__ float rows[QCH * 129];  // 64 channels x 128 floats, pad stride 129
  const float4* base = (const float4*)(img +
      (((size_t)v * C_ + cg * QCH) * H_ + y) * W_);
  // channel rows are H*W floats apart = 4096 float4 apart
#pragma unroll
  for (int i = 0; i < 8; ++i) {
    int f4 = i * 256 + t;      // flat float4 index over the 64x32 f4 slab
    int ch = f4 >> 5;          // 32 float4 per channel row
    int xo4 = f4 & 31;
    float4 u = base[(size_t)ch * (H_ * W_ / 4) + xo4];
    float* dst = &rows[ch * 129 + xo4 * 4];
    dst[0] = u.x; dst[1] = u.y; dst[2] = u.z; dst[3] = u.w;
  }
  __syncthreads();
  // Distribution: wave w handles items w, w+4, w+8, ... ; 64 lanes = 64 ch.
  int w = t >> 6;
  int lane = t & 63;
  for (int it = w; it < cnt; it += 4) {
    int meta = rmeta[b * RCAP + it];
    float s = rscale[b * RCAP + it];
    int m = meta & 511;
    int x = (meta >> 9) & 127;
    float val = rows[lane * 129 + x] * s;   // Δ129 per lane -> conflict-free
    atomicAdd(&msum[(size_t)m * C_ + cg * QCH + lane], val);
  }
}

// ---------------------------------------------------------------------------
// Kernel 3: mW1[m] = (where(mcnt>0, msum/max(mcnt,1), 0)) @ W1   (512 x 128)
__global__ void maskw1_kernel(const float* __restrict__ msum,
                              const float* __restrict__ mcnt,
                              const float* __restrict__ W1,
                              float* __restrict__ mW1) {
  int m = blockIdx.x;        // 0..M-1
  int j = threadIdx.x;       // 0..HD-1
  __shared__ float row[C_];
  row[j] = msum[(size_t)m * C_ + j];
  row[j + HD] = msum[(size_t)m * C_ + j + HD];
  __syncthreads();
  float cv = mcnt[m];
  float inv = cv > 0.f ? 1.0f / fmaxf(cv, 1.0f) : 0.f;
  float acc = 0.f;
  for (int c = 0; c < C_; ++c) {
    acc += row[c] * W1[(size_t)c * HD + j];
  }
  mW1[(size_t)m * HD + j] = acc * inv;
}

// ---------------------------------------------------------------------------
// Kernel 4: one wave per point. Gather & sum the point's mW1 rows (avg 2.5,
// L2-resident 256KB table), relu(mean + b1) into LDS, then 20 lanes do the
// 128x20 layer-2 matvec and write the 20 outputs. No atomics, no fsum buffer.
__global__ void point_mlp_kernel(const int* __restrict__ pcount,
                                 const int* __restrict__ pitems,
                                 const float* __restrict__ mW1,
                                 const float* __restrict__ b1,
                                 const float* __restrict__ W2,
                                 const float* __restrict__ b2,
                                 float* __restrict__ out) {
  int wave = threadIdx.x >> 6;
  int lane = threadIdx.x & 63;
  int p = blockIdx.x * 4 + wave;   // N = 80000 = 20000*4 exactly
  __shared__ float hbuf[4][130];
  int cnt = pcount[p];
  int k = cnt < PCAP ? cnt : PCAP;
  float hx = 0.f, hy = 0.f;
  const int* lst = &pitems[(size_t)p * PCAP];
  for (int it = 0; it < k; ++it) {
    int m = lst[it];
    float2 r = ((const float2*)(mW1 + (size_t)m * HD))[lane];
    hx += r.x;
    hy += r.y;
  }
  float invc = 1.0f / fmaxf((float)cnt, 1e-6f);
  hbuf[wave][2 * lane]     = fmaxf(hx * invc + b1[2 * lane], 0.f);
  hbuf[wave][2 * lane + 1] = fmaxf(hy * invc + b1[2 * lane + 1], 0.f);
  __syncthreads();
  if (lane < L_) {
    float o = b2[lane];
    const float* hb = hbuf[wave];
#pragma unroll 8
    for (int kk = 0; kk < HD; ++kk) o += hb[kk] * W2[kk * L_ + lane];
    out[(size_t)p * L_ + lane] = o;
  }
}

// ---------------------------------------------------------------------------
extern "C" void kernel_launch(void* const* d_in, const int* in_sizes, int n_in,
                              void* d_out, int out_size, void* d_ws, size_t ws_size,
                              hipStream_t stream) {
  const float* img      = (const float*)d_in[0];
  const float* is_seen  = (const float*)d_in[1];
  const float* W1       = (const float*)d_in[2];
  const float* b1       = (const float*)d_in[3];
  const float* W2       = (const float*)d_in[4];
  const float* b2       = (const float*)d_in[5];
  const int* coords     = (const int*)d_in[6];
  const int* centers    = (const int*)d_in[7];
  const int* g2m        = (const int*)d_in[8];
  const int* pair_mask  = (const int*)d_in[9];
  const int* pair_point = (const int*)d_in[10];
  float* out = (float*)d_out;

  // Workspace layout:
  // floats: msum[M*C] | mcnt[M] | mW1[M*HD] | rscale[NROW*RCAP]
  // ints  : rcount[NROW] | pcount[N] | rmeta[NROW*RCAP] | pitems[N*PCAP]
  float* ws     = (float*)d_ws;
  float* msum   = ws;
  float* mcnt   = msum + (size_t)M_ * C_;
  float* mW1    = mcnt + M_;
  float* rscale = mW1 + (size_t)M_ * HD;
  int*   rcount = (int*)(rscale + (size_t)NROW * RCAP);
  int*   pcount = rcount + NROW;
  int*   rmeta  = pcount + N_;
  int*   pitems = rmeta + (size_t)NROW * RCAP;

  // Zero accumulators + counters (2 contiguous memsets; run every call)
  hipMemsetAsync(msum, 0, ((size_t)M_ * C_ + M_) * sizeof(float), stream);
  hipMemsetAsync(rcount, 0, ((size_t)NROW + N_) * sizeof(int), stream);

  build_kernel<<<(GV + E_ + 255) / 256, 256, 0, stream>>>(
      is_seen, coords, centers, g2m, pair_mask, pair_point,
      rcount, rmeta, rscale, pcount, pitems, mcnt);
  gather_kernel<<<NROW * 4, 256, 0, stream>>>(img, rcount, rmeta, rscale, msum);
  maskw1_kernel<<<M_, HD, 0, stream>>>(msum, mcnt, W1, mW1);
  point_mlp_kernel<<<N_ / 4, 256, 0, stream>>>(pcount, pitems, mW1, b1, W2, b2, out);
}

// Round 7
// 176.568 us; speedup vs baseline: 1.2696x; 1.0157x over previous
//
#include <hip/hip_runtime.h>

// Problem constants (from reference)
#define V_ 12
#define N_ 80000
#define C_ 256
#define H_ 128
#define W_ 128
#define G_ 4096
#define M_ 512
#define E_ 200000
#define L_ 20
#define HD 128            // C/2 hidden dim
#define NROW (V_ * H_)    // row-buckets: (v, y) ; 1536
#define RCAP 128          // max items per row-bucket (Poisson λ=32; P(>128) ~ e^-81)
#define PCAP 32           // max pairs per point (Poisson λ=2.5; P(>=32) ~ 1e-19)
#define GV (G_ * V_)
#define QCH 64            // channels per gather block (quarter of C)
// Zero-init region: msum[M*C] + mcnt[M] + rcount[NROW] + pcount[N] (contiguous)
#define NZERO (M_ * C_ + M_ + NROW + N_)   // 213,120 words (mult of 4)

// ---------------------------------------------------------------------------
// Kernel 0: zero the accumulator/counter region. Replaces two in-graph
// hipMemsetAsync nodes whose rocclr fill kernels profiled at 113-118 us.
__global__ void init_kernel(float4* __restrict__ z) {
  int i = blockIdx.x * blockDim.x + threadIdx.x;
  if (i < NZERO / 4) z[i] = make_float4(0.f, 0.f, 0.f, 0.f);
}

// ---------------------------------------------------------------------------
// Kernel 1: build both inverted indexes in one pass.
//  t < GV          : (g,v) item -> row-bucket b=(v,y); store {m, x, scale}
//  GV <= t < GV+E  : pair e -> per-point list; store mask id
// Also accumulates mcnt[m] (groups per mask) from the v==0 thread of each g.
__global__ void build_kernel(const float* __restrict__ is_seen,
                             const int* __restrict__ coords,
                             const int* __restrict__ centers,
                             const int* __restrict__ g2m,
                             const int* __restrict__ pair_mask,
                             const int* __restrict__ pair_point,
                             int* __restrict__ rcount,
                             int* __restrict__ rmeta,
                             float* __restrict__ rscale,
                             int* __restrict__ pcount,
                             int* __restrict__ pitems,
                             float* __restrict__ mcnt) {
  int t = blockIdx.x * blockDim.x + threadIdx.x;
  if (t < GV) {
    int g = t & (G_ - 1);   // g fast -> coalesced-ish centers reads
    int v = t >> 12;
    int n = centers[g];
    float wsum = 0.f;
#pragma unroll
    for (int vv = 0; vv < V_; ++vv) wsum += is_seen[(size_t)vv * N_ + n];
    float s = is_seen[(size_t)v * N_ + n] / (wsum + 1e-6f);
    int m = g2m[g];
    if (v == 0) atomicAdd(&mcnt[m], 1.0f);
    int x = coords[((size_t)v * N_ + n) * 2 + 0];
    int y = coords[((size_t)v * N_ + n) * 2 + 1];
    int b = (v << 7) | y;
    int slot = atomicAdd(&rcount[b], 1);
    if (slot < RCAP) {
      rmeta[b * RCAP + slot] = m | (x << 9);  // m:9 bits, x:7 bits
      rscale[b * RCAP + slot] = s;
    }
  } else if (t < GV + E_) {
    int e = t - GV;
    int p = pair_point[e];
    int slot = atomicAdd(&pcount[p], 1);
    if (slot < PCAP) pitems[(size_t)p * PCAP + slot] = pair_mask[e];
  }
}

// ---------------------------------------------------------------------------
// Kernel 2: row-bucket gather, INSTRUCTION-COALESCED. One block per (v,y) x
// 64-channel quarter. The 64ch x 128float slab is loaded by flat float4 index
// with CONSECUTIVE LANES ON CONSECUTIVE ADDRESSES: each 64-lane instruction
// covers 1 KB contiguous = 16 cache lines (4 lanes/line merged at TCP),
// instead of 64 scattered lines. LDS tile stride 129: distribution reads
// conflict-free; write phase 4-way (hidden under the memory stream).
__global__ void gather_kernel(const float* __restrict__ img,
                              const int* __restrict__ rcount,
                              const int* __restrict__ rmeta,
                              const float* __restrict__ rscale,
                              float* __restrict__ msum) {
  int bid = blockIdx.x;
  int b = bid >> 2;            // row-bucket (v,y)
  int cg = bid & 3;            // channel quarter: ch in [cg*64, cg*64+64)
  int cnt = rcount[b];
  if (cnt == 0) return;        // uniform branch
  if (cnt > RCAP) cnt = RCAP;
  int v = b >> 7;
  int y = b & 127;
  int t = threadIdx.x;
  __shared__ float rows[QCH * 129];  // 64 channels x 128 floats, pad stride 129
  const float4* base = (const float4*)(img +
      (((size_t)v * C_ + cg * QCH) * H_ + y) * W_);
  // channel rows are H*W floats apart = 4096 float4 apart
#pragma unroll
  for (int i = 0; i < 8; ++i) {
    int f4 = i * 256 + t;      // flat float4 index over the 64x32 f4 slab
    int ch = f4 >> 5;          // 32 float4 per channel row
    int xo4 = f4 & 31;
    float4 u = base[(size_t)ch * (H_ * W_ / 4) + xo4];
    float* dst = &rows[ch * 129 + xo4 * 4];
    dst[0] = u.x; dst[1] = u.y; dst[2] = u.z; dst[3] = u.w;
  }
  __syncthreads();
  // Distribution: wave w handles items w, w+4, w+8, ... ; 64 lanes = 64 ch.
  int w = t >> 6;
  int lane = t & 63;
  for (int it = w; it < cnt; it += 4) {
    int meta = rmeta[b * RCAP + it];
    float s = rscale[b * RCAP + it];
    int m = meta & 511;
    int x = (meta >> 9) & 127;
    float val = rows[lane * 129 + x] * s;   // Δ129 per lane -> conflict-free
    atomicAdd(&msum[(size_t)m * C_ + cg * QCH + lane], val);
  }
}

// ---------------------------------------------------------------------------
// Kernel 3: mW1[m] = (where(mcnt>0, msum/max(mcnt,1), 0)) @ W1   (512 x 128)
__global__ void maskw1_kernel(const float* __restrict__ msum,
                              const float* __restrict__ mcnt,
                              const float* __restrict__ W1,
                              float* __restrict__ mW1) {
  int m = blockIdx.x;        // 0..M-1
  int j = threadIdx.x;       // 0..HD-1
  __shared__ float row[C_];
  row[j] = msum[(size_t)m * C_ + j];
  row[j + HD] = msum[(size_t)m * C_ + j + HD];
  __syncthreads();
  float cv = mcnt[m];
  float inv = cv > 0.f ? 1.0f / fmaxf(cv, 1.0f) : 0.f;
  float acc = 0.f;
  for (int c = 0; c < C_; ++c) {
    acc += row[c] * W1[(size_t)c * HD + j];
  }
  mW1[(size_t)m * HD + j] = acc * inv;
}

// ---------------------------------------------------------------------------
// Kernel 4: one wave per point. Gather & sum the point's mW1 rows (avg 2.5,
// L2-resident 256KB table), relu(mean + b1) into LDS, then 20 lanes do the
// 128x20 layer-2 matvec and write the 20 outputs. No atomics, no fsum buffer.
__global__ void point_mlp_kernel(const int* __restrict__ pcount,
                                 const int* __restrict__ pitems,
                                 const float* __restrict__ mW1,
                                 const float* __restrict__ b1,
                                 const float* __restrict__ W2,
                                 const float* __restrict__ b2,
                                 float* __restrict__ out) {
  int wave = threadIdx.x >> 6;
  int lane = threadIdx.x & 63;
  int p = blockIdx.x * 4 + wave;   // N = 80000 = 20000*4 exactly
  __shared__ float hbuf[4][130];
  int cnt = pcount[p];
  int k = cnt < PCAP ? cnt : PCAP;
  float hx = 0.f, hy = 0.f;
  const int* lst = &pitems[(size_t)p * PCAP];
  for (int it = 0; it < k; ++it) {
    int m = lst[it];
    float2 r = ((const float2*)(mW1 + (size_t)m * HD))[lane];
    hx += r.x;
    hy += r.y;
  }
  float invc = 1.0f / fmaxf((float)cnt, 1e-6f);
  hbuf[wave][2 * lane]     = fmaxf(hx * invc + b1[2 * lane], 0.f);
  hbuf[wave][2 * lane + 1] = fmaxf(hy * invc + b1[2 * lane + 1], 0.f);
  __syncthreads();
  if (lane < L_) {
    float o = b2[lane];
    const float* hb = hbuf[wave];
#pragma unroll 8
    for (int kk = 0; kk < HD; ++kk) o += hb[kk] * W2[kk * L_ + lane];
    out[(size_t)p * L_ + lane] = o;
  }
}

// ---------------------------------------------------------------------------
extern "C" void kernel_launch(void* const* d_in, const int* in_sizes, int n_in,
                              void* d_out, int out_size, void* d_ws, size_t ws_size,
                              hipStream_t stream) {
  const float* img      = (const float*)d_in[0];
  const float* is_seen  = (const float*)d_in[1];
  const float* W1       = (const float*)d_in[2];
  const float* b1       = (const float*)d_in[3];
  const float* W2       = (const float*)d_in[4];
  const float* b2       = (const float*)d_in[5];
  const int* coords     = (const int*)d_in[6];
  const int* centers    = (const int*)d_in[7];
  const int* g2m        = (const int*)d_in[8];
  const int* pair_mask  = (const int*)d_in[9];
  const int* pair_point = (const int*)d_in[10];
  float* out = (float*)d_out;

  // Workspace layout — zero-init region FIRST and contiguous:
  //   msum[M*C] | mcnt[M] | rcount[NROW] | pcount[N]     <- zeroed by init_kernel
  //   mW1[M*HD] | rscale[NROW*RCAP] | rmeta[NROW*RCAP] | pitems[N*PCAP]
  float* ws     = (float*)d_ws;
  float* msum   = ws;
  float* mcnt   = msum + (size_t)M_ * C_;
  int*   rcount = (int*)(mcnt + M_);
  int*   pcount = rcount + NROW;
  float* mW1    = (float*)(pcount + N_);
  float* rscale = mW1 + (size_t)M_ * HD;
  int*   rmeta  = (int*)(rscale + (size_t)NROW * RCAP);
  int*   pitems = rmeta + (size_t)NROW * RCAP;

  init_kernel<<<(NZERO / 4 + 255) / 256, 256, 0, stream>>>((float4*)ws);
  build_kernel<<<(GV + E_ + 255) / 256, 256, 0, stream>>>(
      is_seen, coords, centers, g2m, pair_mask, pair_point,
      rcount, rmeta, rscale, pcount, pitems, mcnt);
  gather_kernel<<<NROW * 4, 256, 0, stream>>>(img, rcount, rmeta, rscale, msum);
  maskw1_kernel<<<M_, HD, 0, stream>>>(msum, mcnt, W1, mW1);
  point_mlp_kernel<<<N_ / 4, 256, 0, stream>>>(pcount, pitems, mW1, b1, W2, b2, out);
}